// Round 1
// baseline (4232.578 us; speedup 1.0000x reference)
//
#include <hip/hip_runtime.h>
#include <hip/hip_bf16.h>

// Problem constants
#define Bn 4096
#define Ln 64
#define Mn 128
#define Pn 128
#define Tn 64
#define NB 8
#define NTH 512

// ---------------- helpers ----------------
__device__ __forceinline__ float rdl(float v, int l) {
  return __int_as_float(__builtin_amdgcn_readlane(__float_as_int(v), l));
}
__device__ __forceinline__ float bf_lo(unsigned u) { return __uint_as_float(u << 16); }
__device__ __forceinline__ float bf_hi(unsigned u) { return __uint_as_float(u & 0xffff0000u); }
__device__ __forceinline__ unsigned pack2(float a, float b) {
  unsigned ua = __float_as_uint(a), ub = __float_as_uint(b);
  ua = (ua + 0x7fffu + ((ua >> 16) & 1)) >> 16;
  ub = (ub + 0x7fffu + ((ub >> 16) & 1)) >> 16;
  return (ua & 0xffffu) | (ub << 16);
}
__device__ __forceinline__ float fast_rcp(float x) { return __builtin_amdgcn_rcpf(x); }
__device__ __forceinline__ float fast_tanh(float x) {
  float e = __expf(2.f * x);
  return 1.f - 2.f * fast_rcp(1.f + e);
}
__device__ __forceinline__ float fast_sig(float x) {
  return fast_rcp(1.f + __expf(-x));
}

// ---------------- weight pre-pack ----------------
// ws layout (bytes):
//   Wd_pk  bf16 [k2<128][lane<64][4]            @ 0        (65536 B)
//   Whh_pk bf16 [k<128][lane<64][8]             @ 65536    (131072 B)
//   Wdec_pk bf16 [t<64][j<128][lane<64][2]      @ 196608   (2097152 B)
//   Wy_pk  f32  [k<256][lane<64][2]             @ 2293760  (131072 B)
//   UdT    f32  [k<128][m<128]                  @ 2424832  (65536 B)
__global__ void pack_weights(const float* __restrict__ W_d_w,
                             const float* __restrict__ W_hh,
                             const float* __restrict__ W_dec_w,
                             const float* __restrict__ W_y_w,
                             const float* __restrict__ U_d_w,
                             __hip_bfloat16* __restrict__ Wd_pk,
                             __hip_bfloat16* __restrict__ Whh_pk,
                             __hip_bfloat16* __restrict__ Wdec_pk,
                             float* __restrict__ Wy_pk,
                             float* __restrict__ UdT) {
  const int i0 = blockIdx.x * blockDim.x + threadIdx.x;
  const int stride = gridDim.x * blockDim.x;
  for (int i = i0; i < 32768; i += stride) {  // Wd
    int k2 = i >> 8, lane = (i >> 2) & 63, q = i & 3;
    int m = lane + (q >> 1) * 64, k = 2 * k2 + (q & 1);
    Wd_pk[i] = __float2bfloat16(W_d_w[m * 256 + k]);
  }
  for (int i = i0; i < 65536; i += stride) {  // Whh
    int k = i >> 9, lane = (i >> 3) & 63, c = i & 7;
    Whh_pk[i] = __float2bfloat16(W_hh[(c * 64 + lane) * 128 + k]);
  }
  for (int i = i0; i < 1048576; i += stride) {  // Wdec (blocks 1..64)
    int t = i >> 14, j = (i >> 7) & 127, lane = (i >> 1) & 63, q = i & 1;
    Wdec_pk[i] = __float2bfloat16(W_dec_w[(q * 64 + lane) * (128 * 65) + (t + 1) * 128 + j]);
  }
  for (int i = i0; i < 32768; i += stride) {  // Wy (f32)
    int k = i >> 7, lane = (i >> 1) & 63, q = i & 1;
    Wy_pk[i] = W_y_w[(q * 64 + lane) * 256 + k];
  }
  for (int i = i0; i < 16384; i += stride) {  // U_d transposed
    int k = i >> 7, m = i & 127;
    UdT[i] = U_d_w[m * 128 + k];
  }
}

// ---------------- fused scan ----------------
// LDS: y1 bf16 packed [bb][m8<16][l<64][8]  131072 B @ 0
//      enc_s bf16 swizzled [l][kx]           16384 B @ 131072 (phase 0 only)
//      e_proj f32 [bb][l]                     2048 B @ 147456
#define LDS_BYTES 149504

__global__ __launch_bounds__(NTH, 2) void fused_main(
    const float* __restrict__ enc, const float* __restrict__ y,
    const float* __restrict__ W_d_b, const float* __restrict__ v_d_w,
    const float* __restrict__ w_tilda_w, const float* __restrict__ w_tilda_b,
    const float* __restrict__ W_ih, const float* __restrict__ b_ih,
    const float* __restrict__ b_hh, const float* __restrict__ W_dec_b,
    const float* __restrict__ W_y_b, const float* __restrict__ v_y_w,
    const float* __restrict__ v_y_b,
    const __hip_bfloat16* __restrict__ Wd_pk,
    const __hip_bfloat16* __restrict__ Whh_pk,
    const __hip_bfloat16* __restrict__ Wdec_pk,
    const float* __restrict__ Wy_pk, const float* __restrict__ UdT,
    float* __restrict__ out) {
  extern __shared__ char lds[];
  unsigned* y1u = (unsigned*)lds;
  unsigned short* enc_s = (unsigned short*)(lds + 131072);
  float* e_proj_s = (float*)(lds + 147456);

  const int tid = threadIdx.x;
  const int lane = tid & 63;
  const int w = tid >> 6;
  const int b0 = blockIdx.x * NB;

  // ---------- Phase 0: y1 (bf16, [m][l] packed) + e_proj ----------
  for (int bb = 0; bb < NB; ++bb) {
    const int b = b0 + bb;
    for (int i = tid; i < Ln * Mn; i += NTH) {
      int l = i >> 7, k = i & 127;
      float v = enc[((size_t)b * Ln + l) * Mn + k];
      int kx = k ^ ((l & 63) << 1);  // bank swizzle, keeps even pairs adjacent
      unsigned uv = __float_as_uint(v);
      uv = (uv + 0x7fffu + ((uv >> 16) & 1)) >> 16;
      enc_s[l * 128 + kx] = (unsigned short)uv;
    }
    __syncthreads();
    for (int rep = 0; rep < 2; ++rep) {
      const int m8 = w + rep * 8;
      float acc0 = 0.f, acc1 = 0.f, acc2 = 0.f, acc3 = 0.f;
      float acc4 = 0.f, acc5 = 0.f, acc6 = 0.f, acc7 = 0.f;
      for (int k = 0; k < 128; k += 2) {
        int kx = k ^ ((lane & 63) << 1);
        unsigned uu = *(const unsigned*)(enc_s + lane * 128 + kx);
        float e0 = bf_lo(uu), e1 = bf_hi(uu);
        const float4 a0 = *((const float4*)(UdT + k * 128 + m8 * 8));
        const float4 a1 = *((const float4*)(UdT + k * 128 + m8 * 8 + 4));
        const float4 b0v = *((const float4*)(UdT + (k + 1) * 128 + m8 * 8));
        const float4 b1v = *((const float4*)(UdT + (k + 1) * 128 + m8 * 8 + 4));
        acc0 += e0 * a0.x + e1 * b0v.x; acc1 += e0 * a0.y + e1 * b0v.y;
        acc2 += e0 * a0.z + e1 * b0v.z; acc3 += e0 * a0.w + e1 * b0v.w;
        acc4 += e0 * a1.x + e1 * b1v.x; acc5 += e0 * a1.y + e1 * b1v.y;
        acc6 += e0 * a1.z + e1 * b1v.z; acc7 += e0 * a1.w + e1 * b1v.w;
      }
      uint4 pk;
      pk.x = pack2(acc0, acc1); pk.y = pack2(acc2, acc3);
      pk.z = pack2(acc4, acc5); pk.w = pack2(acc6, acc7);
      *((uint4*)(y1u + ((bb * 16 + m8) * 64 + lane) * 4)) = pk;
    }
    if (w == 0) {
      float a = 0.f;
      for (int k = 0; k < 128; ++k) {
        int kx = k ^ ((lane & 63) << 1);
        a += __uint_as_float(((unsigned)enc_s[lane * 128 + kx]) << 16) * w_tilda_w[k];
      }
      e_proj_s[bb * 64 + lane] = a;
    }
    __syncthreads();
  }

  // ---------- Phase 1: per-wave scan over T ----------
  const int bb = w;
  const int b = b0 + bb;
  float d_lo = 0.f, d_hi = 0.f, s_lo = 0.f, s_hi = 0.f;
  float dfin_lo = W_dec_b[lane], dfin_hi = W_dec_b[lane + 64];
  const float vd_lo = v_d_w[lane], vd_hi = v_d_w[lane + 64];
  const float eproj = e_proj_s[bb * 64 + lane];
  const float wdb_lo = W_d_b[lane], wdb_hi = W_d_b[lane + 64];
  float bias[8], wih[8];
#pragma unroll
  for (int c = 0; c < 8; ++c) {
    bias[c] = b_ih[c * 64 + lane] + b_hh[c * 64 + lane];
    wih[c] = W_ih[c * 64 + lane];
  }
  const float wt_y = w_tilda_w[128];
  const float wt_b0 = w_tilda_b[0];
  float beta_sv = 0.f;

  const unsigned* Wd_u = (const unsigned*)Wd_pk;
  const unsigned* Whh_u = (const unsigned*)Whh_pk;
  const unsigned* Wdec_u = (const unsigned*)Wdec_pk;

  for (int t = 0; t < Tn; ++t) {
    __syncthreads();  // phase-lock waves: shared weight stream stays L1-hot

    // ---- x1 = [d;s] @ W_d^T + b ----
    float a_lo = wdb_lo, a_hi = wdb_hi;
#pragma unroll 8
    for (int k2 = 0; k2 < 32; ++k2) {
      float f0 = rdl(d_lo, 2 * k2), f1 = rdl(d_lo, 2 * k2 + 1);
      uint2 u = *((const uint2*)(Wd_u + (k2 * 64 + lane) * 2));
      a_lo += f0 * bf_lo(u.x) + f1 * bf_hi(u.x);
      a_hi += f0 * bf_lo(u.y) + f1 * bf_hi(u.y);
    }
#pragma unroll 8
    for (int k2 = 32; k2 < 64; ++k2) {
      float f0 = rdl(d_hi, 2 * k2 - 64), f1 = rdl(d_hi, 2 * k2 - 63);
      uint2 u = *((const uint2*)(Wd_u + (k2 * 64 + lane) * 2));
      a_lo += f0 * bf_lo(u.x) + f1 * bf_hi(u.x);
      a_hi += f0 * bf_lo(u.y) + f1 * bf_hi(u.y);
    }
#pragma unroll 8
    for (int k2 = 64; k2 < 96; ++k2) {
      float f0 = rdl(s_lo, 2 * k2 - 128), f1 = rdl(s_lo, 2 * k2 - 127);
      uint2 u = *((const uint2*)(Wd_u + (k2 * 64 + lane) * 2));
      a_lo += f0 * bf_lo(u.x) + f1 * bf_hi(u.x);
      a_hi += f0 * bf_lo(u.y) + f1 * bf_hi(u.y);
    }
#pragma unroll 8
    for (int k2 = 96; k2 < 128; ++k2) {
      float f0 = rdl(s_hi, 2 * k2 - 192), f1 = rdl(s_hi, 2 * k2 - 191);
      uint2 u = *((const uint2*)(Wd_u + (k2 * 64 + lane) * 2));
      a_lo += f0 * bf_lo(u.x) + f1 * bf_hi(u.x);
      a_hi += f0 * bf_lo(u.y) + f1 * bf_hi(u.y);
    }
    const float x1_lo = a_lo, x1_hi = a_hi;

    // ---- z = tanh(x1 + y1), logits (lane = l) ----
    float lg = 0.f;
#pragma unroll
    for (int m8 = 0; m8 < 16; ++m8) {
      const uint4 u = *((const uint4*)(y1u + ((bb * 16 + m8) * 64 + lane) * 4));
#define ZSTEP(UU, QQ)                                                        \
      {                                                                      \
        const int m0 = m8 * 8 + 2 * (QQ);                                    \
        float xa = (m0 < 64) ? rdl(x1_lo, m0) : rdl(x1_hi, m0 - 64);         \
        float xb = (m0 < 64) ? rdl(x1_lo, m0 + 1) : rdl(x1_hi, m0 - 63);     \
        float va = (m0 < 64) ? rdl(vd_lo, m0) : rdl(vd_hi, m0 - 64);         \
        float vb = (m0 < 64) ? rdl(vd_lo, m0 + 1) : rdl(vd_hi, m0 - 63);     \
        lg += va * fast_tanh(xa + bf_lo(UU));                                \
        lg += vb * fast_tanh(xb + bf_hi(UU));                                \
      }
      ZSTEP(u.x, 0) ZSTEP(u.y, 1) ZSTEP(u.z, 2) ZSTEP(u.w, 3)
#undef ZSTEP
    }

    // ---- softmax over l (in-wave), y_til ----
    float mx = lg;
#pragma unroll
    for (int off = 32; off > 0; off >>= 1) mx = fmaxf(mx, __shfl_xor(mx, off, 64));
    float p = __expf(lg - mx);
    float sm = p, yt = p * eproj;
#pragma unroll
    for (int off = 32; off > 0; off >>= 1) {
      sm += __shfl_xor(sm, off, 64);
      yt += __shfl_xor(yt, off, 64);
    }
    float rs = fast_rcp(sm);
    beta_sv = p * rs;
    float ytil = yt * rs + y[(size_t)b * Tn + t] * wt_y + wt_b0;

    // ---- gates = y_til*W_ih + b + d @ W_hh^T ----
    float g0 = bias[0] + ytil * wih[0], g1 = bias[1] + ytil * wih[1];
    float g2 = bias[2] + ytil * wih[2], g3 = bias[3] + ytil * wih[3];
    float g4 = bias[4] + ytil * wih[4], g5 = bias[5] + ytil * wih[5];
    float g6 = bias[6] + ytil * wih[6], g7 = bias[7] + ytil * wih[7];
#pragma unroll 4
    for (int k = 0; k < 64; ++k) {
      float f = rdl(d_lo, k);
      uint4 u = *((const uint4*)(Whh_u + (k * 64 + lane) * 4));
      g0 += f * bf_lo(u.x); g1 += f * bf_hi(u.x);
      g2 += f * bf_lo(u.y); g3 += f * bf_hi(u.y);
      g4 += f * bf_lo(u.z); g5 += f * bf_hi(u.z);
      g6 += f * bf_lo(u.w); g7 += f * bf_hi(u.w);
    }
#pragma unroll 4
    for (int k = 64; k < 128; ++k) {
      float f = rdl(d_hi, k - 64);
      uint4 u = *((const uint4*)(Whh_u + (k * 64 + lane) * 4));
      g0 += f * bf_lo(u.x); g1 += f * bf_hi(u.x);
      g2 += f * bf_lo(u.y); g3 += f * bf_hi(u.y);
      g4 += f * bf_lo(u.z); g5 += f * bf_hi(u.z);
      g6 += f * bf_lo(u.w); g7 += f * bf_hi(u.w);
    }

    // ---- LSTM pointwise ----
    float ii0 = fast_sig(g0), ii1 = fast_sig(g1);
    float ff0 = fast_sig(g2), ff1 = fast_sig(g3);
    float gg0 = fast_tanh(g4), gg1 = fast_tanh(g5);
    float oo0 = fast_sig(g6), oo1 = fast_sig(g7);
    s_lo = ff0 * s_lo + ii0 * gg0;
    s_hi = ff1 * s_hi + ii1 * gg1;
    d_lo = oo0 * fast_tanh(s_lo);
    d_hi = oo1 * fast_tanh(s_hi);

    // ---- on-line W_dec accumulation (block t+1) ----
    const unsigned* wdp = Wdec_u + t * (128 * 64);
#pragma unroll 4
    for (int j = 0; j < 64; ++j) {
      float f = rdl(d_lo, j);
      unsigned u = wdp[j * 64 + lane];
      dfin_lo += f * bf_lo(u);
      dfin_hi += f * bf_hi(u);
    }
#pragma unroll 4
    for (int j = 64; j < 128; ++j) {
      float f = rdl(d_hi, j - 64);
      unsigned u = wdp[j * 64 + lane];
      dfin_lo += f * bf_lo(u);
      dfin_hi += f * bf_hi(u);
    }
  }

  // ---------- Phase 2: c_T, final head ----------
  float c_lo = 0.f, c_hi = 0.f;
  for (int l = 0; l < 64; ++l) {
    float be = rdl(beta_sv, l);
    const float* er = enc + ((size_t)b * 64 + l) * 128;
    c_lo += be * er[lane];
    c_hi += be * er[lane + 64];
  }
  float h_lo = W_y_b[lane], h_hi = W_y_b[lane + 64];
  const float2* wy = (const float2*)Wy_pk;
  for (int k = 0; k < 64; ++k) {
    float f = rdl(dfin_lo, k);
    float2 u = wy[k * 64 + lane];
    h_lo += f * u.x; h_hi += f * u.y;
  }
  for (int k = 64; k < 128; ++k) {
    float f = rdl(dfin_hi, k - 64);
    float2 u = wy[k * 64 + lane];
    h_lo += f * u.x; h_hi += f * u.y;
  }
  for (int k = 128; k < 192; ++k) {
    float f = rdl(c_lo, k - 128);
    float2 u = wy[k * 64 + lane];
    h_lo += f * u.x; h_hi += f * u.y;
  }
  for (int k = 192; k < 256; ++k) {
    float f = rdl(c_hi, k - 192);
    float2 u = wy[k * 64 + lane];
    h_lo += f * u.x; h_hi += f * u.y;
  }
  float r = h_lo * v_y_w[lane] + h_hi * v_y_w[lane + 64];
#pragma unroll
  for (int off = 32; off > 0; off >>= 1) r += __shfl_xor(r, off, 64);
  if (lane == 0) out[b] = r + v_y_b[0];
}

extern "C" void kernel_launch(void* const* d_in, const int* in_sizes, int n_in,
                              void* d_out, int out_size, void* d_ws, size_t ws_size,
                              hipStream_t stream) {
  const float* enc = (const float*)d_in[0];
  const float* y = (const float*)d_in[1];
  const float* W_d_w = (const float*)d_in[2];
  const float* W_d_b = (const float*)d_in[3];
  const float* U_d_w = (const float*)d_in[4];
  const float* v_d_w = (const float*)d_in[5];
  const float* w_tilda_w = (const float*)d_in[6];
  const float* w_tilda_b = (const float*)d_in[7];
  const float* W_ih = (const float*)d_in[8];
  const float* b_ih = (const float*)d_in[9];
  const float* W_hh = (const float*)d_in[10];
  const float* b_hh = (const float*)d_in[11];
  const float* W_dec_w = (const float*)d_in[12];
  const float* W_dec_b = (const float*)d_in[13];
  const float* W_y_w = (const float*)d_in[14];
  const float* W_y_b = (const float*)d_in[15];
  const float* v_y_w = (const float*)d_in[16];
  const float* v_y_b = (const float*)d_in[17];

  char* ws = (char*)d_ws;
  __hip_bfloat16* Wd_pk = (__hip_bfloat16*)(ws + 0);
  __hip_bfloat16* Whh_pk = (__hip_bfloat16*)(ws + 65536);
  __hip_bfloat16* Wdec_pk = (__hip_bfloat16*)(ws + 196608);
  float* Wy_pk = (float*)(ws + 2293760);
  float* UdT = (float*)(ws + 2424832);

  pack_weights<<<512, 256, 0, stream>>>(W_d_w, W_hh, W_dec_w, W_y_w, U_d_w,
                                        Wd_pk, Whh_pk, Wdec_pk, Wy_pk, UdT);
  fused_main<<<Bn / NB, NTH, LDS_BYTES, stream>>>(
      enc, y, W_d_b, v_d_w, w_tilda_w, w_tilda_b, W_ih, b_ih, b_hh, W_dec_b,
      W_y_b, v_y_w, v_y_b, Wd_pk, Whh_pk, Wdec_pk, Wy_pk, UdT, (float*)d_out);
}

// Round 3
// 2967.571 us; speedup vs baseline: 1.4263x; 1.4263x over previous
//
#include <hip/hip_runtime.h>
#include <hip/hip_bf16.h>

// Problem constants
#define Bn 4096
#define Ln 64
#define Mn 128
#define Pn 128
#define Tn 64
#define NB 8
#define NTH 512

typedef unsigned int u32;
typedef _Float16 h2 __attribute__((ext_vector_type(2)));
typedef __fp16 fp16x2 __attribute__((ext_vector_type(2)));

__device__ __forceinline__ h2 as_h2(u32 u) { union { u32 u; h2 h; } c; c.u = u; return c.h; }
__device__ __forceinline__ u32 as_u32(h2 h) { union { u32 u; h2 h; } c; c.h = h; return c.u; }

#if __has_builtin(__builtin_amdgcn_fdot2)
__device__ __forceinline__ float dot2h(u32 a, u32 w, float acc) {
  return __builtin_amdgcn_fdot2(as_h2(a), as_h2(w), acc, false);
}
#else
__device__ __forceinline__ float dot2h(u32 a, u32 w, float acc) {
  h2 av = as_h2(a), wv = as_h2(w);
  return fmaf((float)av.x, (float)wv.x, fmaf((float)av.y, (float)wv.y, acc));
}
#endif

#if __has_builtin(__builtin_amdgcn_cvt_pkrtz)
__device__ __forceinline__ u32 pkh(float a, float b) {
  union { u32 u; fp16x2 h; } c;
  c.h = __builtin_amdgcn_cvt_pkrtz(a, b);
  return c.u;
}
#else
__device__ __forceinline__ u32 pkh(float a, float b) {
  h2 h; h.x = (_Float16)a; h.y = (_Float16)b; return as_u32(h);
}
#endif

#if __has_builtin(__builtin_amdgcn_exp2f)
#define FEXP(x) __builtin_amdgcn_exp2f(x)
#define CE 2.885390081777927f /* 2*log2(e) */
#else
#define FEXP(x) __expf(x)
#define CE 2.0f
#endif

__device__ __forceinline__ float fast_rcp(float x) { return __builtin_amdgcn_rcpf(x); }
__device__ __forceinline__ float rcp1(float e) { return __builtin_amdgcn_rcpf(1.f + e); }
__device__ __forceinline__ float fast_tanh(float x) {
  float e = __expf(2.f * x);
  return 1.f - 2.f * fast_rcp(1.f + e);
}
__device__ __forceinline__ float fast_sig(float x) {
  return fast_rcp(1.f + __expf(-x));
}

// ---------------- weight pre-pack (all f16 pair layouts) ----------------
// ws layout (bytes):
//   Wd_pk  f16 [k4<64][j<64][u<4][e<2]          @ 0        (65536 B)
//   Whh_pk f16 [k2<64][j<64][u<8][e<2]          @ 65536    (131072 B)
//   Wdec_pk f16 [t<64][k2<64][j<64][q<2][e<2]   @ 196608   (2097152 B)
//   Wy_pk  f32 [k<256][j<64][q<2]               @ 2293760  (131072 B)
//   UdT    f32 [k<128][m<128]                   @ 2424832  (65536 B)
__global__ void pack_weights(const float* __restrict__ W_d_w,
                             const float* __restrict__ W_hh,
                             const float* __restrict__ W_dec_w,
                             const float* __restrict__ W_y_w,
                             const float* __restrict__ U_d_w,
                             _Float16* __restrict__ Wd_pk,
                             _Float16* __restrict__ Whh_pk,
                             _Float16* __restrict__ Wdec_pk,
                             float* __restrict__ Wy_pk,
                             float* __restrict__ UdT) {
  const int i0 = blockIdx.x * blockDim.x + threadIdx.x;
  const int stride = gridDim.x * blockDim.x;
  for (int i = i0; i < 32768; i += stride) {  // Wd: x1[p] = sum_k cat[k]*W_d_w[p,k]
    int e = i & 1, u = (i >> 1) & 3, j = (i >> 3) & 63, k4 = i >> 9;
    int k2 = 2 * k4 + (u >> 1), q = u & 1;
    int p = 2 * j + q, k = 2 * k2 + e;
    Wd_pk[i] = (_Float16)W_d_w[p * 256 + k];
  }
  for (int i = i0; i < 65536; i += stride) {  // Whh: gates[n] = sum_k d[k]*W_hh[n,k]
    int e = i & 1, u = (i >> 1) & 7, j = (i >> 4) & 63, k2 = i >> 10;
    int c = u >> 1, q = u & 1;
    int n = c * 128 + 2 * j + q, k = 2 * k2 + e;
    Whh_pk[i] = (_Float16)W_hh[n * 128 + k];
  }
  for (int i = i0; i < 1048576; i += stride) {  // Wdec blocks 1..64
    int e = i & 1, q = (i >> 1) & 1, j = (i >> 2) & 63, k2 = (i >> 8) & 63, t = i >> 14;
    int p = 2 * j + q, col = (t + 1) * 128 + 2 * k2 + e;
    Wdec_pk[i] = (_Float16)W_dec_w[p * 8320 + col];
  }
  for (int i = i0; i < 32768; i += stride) {  // Wy (f32)
    int q = i & 1, j = (i >> 1) & 63, k = i >> 7;
    int p = 2 * j + q;
    Wy_pk[i] = W_y_w[p * 256 + k];
  }
  for (int i = i0; i < 16384; i += stride) {  // U_d transposed
    int k = i >> 7, m = i & 127;
    UdT[i] = U_d_w[m * 128 + k];
  }
}

// ---------------- fused scan ----------------
// LDS map (bytes):
//   y1u    u32  [bb][m8<16][l<64][4]   131072 @ 0          (f16 pairs, persistent)
//   cat_u  u32  [bb][128]              4096   @ 131072     (d pairs 0..64, s pairs 64..128)
//   x1c_s  f32  [bb][128]              4096   @ 135168     (x1 * CE, broadcast)
//   cat2_s f32  [bb][256]              8192   @ 139264     (phase 2 only)
//   enc_h  f16  [l][128] swizzled      16384  @ 131072     (phase 0 only; aliases the above)
//   e_proj f32  [bb][64]               2048   @ 147456     (beta_s in phase 2)
//   va2_s  f32  [128]                  512    @ 149504
#define LDS_BYTES 150016

__global__ __launch_bounds__(NTH, 2) void fused_main(
    const float* __restrict__ enc, const float* __restrict__ y,
    const float* __restrict__ W_d_b, const float* __restrict__ v_d_w,
    const float* __restrict__ w_tilda_w, const float* __restrict__ w_tilda_b,
    const float* __restrict__ W_ih, const float* __restrict__ b_ih,
    const float* __restrict__ b_hh, const float* __restrict__ W_dec_b,
    const float* __restrict__ W_y_b, const float* __restrict__ v_y_w,
    const float* __restrict__ v_y_b,
    const _Float16* __restrict__ Wd_pk, const _Float16* __restrict__ Whh_pk,
    const _Float16* __restrict__ Wdec_pk, const float* __restrict__ Wy_pk,
    const float* __restrict__ UdT, float* __restrict__ out) {
  extern __shared__ char lds[];
  u32* y1u = (u32*)lds;
  u32* cat_u = (u32*)(lds + 131072);
  float* x1c_s = (float*)(lds + 135168);
  float* cat2_s = (float*)(lds + 139264);
  _Float16* enc_h = (_Float16*)(lds + 131072);
  float* e_proj_s = (float*)(lds + 147456);
  float* va2_s = (float*)(lds + 149504);

  const int tid = threadIdx.x;
  const int lane = tid & 63;
  const int w = tid >> 6;
  const int b0 = blockIdx.x * NB;

  // ---------- Phase 0: y1 (f16 pairs, [m][l]) + e_proj ----------
  for (int bb = 0; bb < NB; ++bb) {
    const int b = b0 + bb;
    for (int i = tid; i < Ln * Mn; i += NTH) {
      int l = i >> 7, k = i & 127;
      float v = enc[((size_t)b * Ln + l) * Mn + k];
      int kx = k ^ (l << 1);  // bank swizzle, keeps even pairs adjacent
      enc_h[l * 128 + kx] = (_Float16)v;
    }
    __syncthreads();
    for (int rep = 0; rep < 2; ++rep) {
      const int m8 = w + rep * 8;
      float acc0 = 0.f, acc1 = 0.f, acc2 = 0.f, acc3 = 0.f;
      float acc4 = 0.f, acc5 = 0.f, acc6 = 0.f, acc7 = 0.f;
      for (int k = 0; k < 128; k += 2) {
        int kx = k ^ (lane << 1);
        u32 uu = *(const u32*)(enc_h + lane * 128 + kx);
        h2 eh = as_h2(uu);
        float e0 = (float)eh.x, e1 = (float)eh.y;
        const float4 a0 = *((const float4*)(UdT + k * 128 + m8 * 8));
        const float4 a1 = *((const float4*)(UdT + k * 128 + m8 * 8 + 4));
        const float4 b0v = *((const float4*)(UdT + (k + 1) * 128 + m8 * 8));
        const float4 b1v = *((const float4*)(UdT + (k + 1) * 128 + m8 * 8 + 4));
        acc0 += e0 * a0.x + e1 * b0v.x; acc1 += e0 * a0.y + e1 * b0v.y;
        acc2 += e0 * a0.z + e1 * b0v.z; acc3 += e0 * a0.w + e1 * b0v.w;
        acc4 += e0 * a1.x + e1 * b1v.x; acc5 += e0 * a1.y + e1 * b1v.y;
        acc6 += e0 * a1.z + e1 * b1v.z; acc7 += e0 * a1.w + e1 * b1v.w;
      }
      uint4 pk;
      pk.x = pkh(acc0, acc1); pk.y = pkh(acc2, acc3);
      pk.z = pkh(acc4, acc5); pk.w = pkh(acc6, acc7);
      *((uint4*)(y1u + ((bb * 16 + m8) * 64 + lane) * 4)) = pk;
    }
    if (w == 0) {
      float a = 0.f;
      for (int k = 0; k < 128; k += 2) {
        int kx = k ^ (lane << 1);
        u32 uu = *(const u32*)(enc_h + lane * 128 + kx);
        h2 eh = as_h2(uu);
        a += (float)eh.x * w_tilda_w[k] + (float)eh.y * w_tilda_w[k + 1];
      }
      e_proj_s[bb * 64 + lane] = a;
    }
    __syncthreads();
  }

  // ---------- init shared state ----------
  const int bb = w;
  const int b = b0 + bb;
  const int j = lane;
  cat_u[bb * 128 + j] = 0u;
  cat_u[bb * 128 + 64 + j] = 0u;
  if (w == 0) {
    va2_s[lane] = 2.f * v_d_w[lane];
    va2_s[64 + lane] = 2.f * v_d_w[64 + lane];
  }

  const float2 wdb = *(const float2*)(W_d_b + 2 * j);
  const float2 dfb = *(const float2*)(W_dec_b + 2 * j);
  float df0a = dfb.x, df0b = 0.f, df1a = dfb.y, df1b = 0.f;
  float s0 = 0.f, s1 = 0.f;
  float bias[8], wih[8];
#pragma unroll
  for (int c = 0; c < 4; ++c) {
    float2 bi = *(const float2*)(b_ih + c * 128 + 2 * j);
    float2 bh = *(const float2*)(b_hh + c * 128 + 2 * j);
    float2 wi = *(const float2*)(W_ih + c * 128 + 2 * j);
    bias[2 * c] = bi.x + bh.x; bias[2 * c + 1] = bi.y + bh.y;
    wih[2 * c] = wi.x; wih[2 * c + 1] = wi.y;
  }
  const float wt_y = w_tilda_w[128];
  const float wt_b0 = w_tilda_b[0];
  const float eproj = e_proj_s[bb * 64 + lane];
  float sv = v_d_w[lane] + v_d_w[64 + lane];
#pragma unroll
  for (int off = 32; off; off >>= 1) sv += __shfl_xor(sv, off, 64);
  float beta_sv = 0.f;

  const uint4* wd4 = (const uint4*)Wd_pk;
  const uint4* whh4 = (const uint4*)Whh_pk;
  const uint2* wdc2 = (const uint2*)Wdec_pk;

  // ---------- Phase 1: scan over T ----------
  for (int t = 0; t < Tn; ++t) {
    __syncthreads();  // phase-lock waves: shared weight stream stays cache-hot

    // ---- x1 = [d;s] @ W_d^T + b (K=256 as 128 pairs) ----
    float a00 = wdb.x, a01 = 0.f, a10 = wdb.y, a11 = 0.f;
#pragma unroll 4
    for (int it = 0; it < 16; ++it) {
      uint4 c0 = *((const uint4*)(cat_u + bb * 128 + it * 8));
      uint4 c1 = *((const uint4*)(cat_u + bb * 128 + it * 8 + 4));
      uint4 w0 = wd4[(it * 4 + 0) * 64 + j];
      uint4 w1 = wd4[(it * 4 + 1) * 64 + j];
      uint4 w2 = wd4[(it * 4 + 2) * 64 + j];
      uint4 w3 = wd4[(it * 4 + 3) * 64 + j];
      a00 = dot2h(c0.x, w0.x, a00); a10 = dot2h(c0.x, w0.y, a10);
      a01 = dot2h(c0.y, w0.z, a01); a11 = dot2h(c0.y, w0.w, a11);
      a00 = dot2h(c0.z, w1.x, a00); a10 = dot2h(c0.z, w1.y, a10);
      a01 = dot2h(c0.w, w1.z, a01); a11 = dot2h(c0.w, w1.w, a11);
      a00 = dot2h(c1.x, w2.x, a00); a10 = dot2h(c1.x, w2.y, a10);
      a01 = dot2h(c1.y, w2.z, a01); a11 = dot2h(c1.y, w2.w, a11);
      a00 = dot2h(c1.z, w3.x, a00); a10 = dot2h(c1.z, w3.y, a10);
      a01 = dot2h(c1.w, w3.z, a01); a11 = dot2h(c1.w, w3.w, a11);
    }
    {
      float x0 = a00 + a01, x1v = a10 + a11;
      *((float2*)(x1c_s + bb * 128 + 2 * j)) = make_float2(x0 * CE, x1v * CE);
    }

    // ---- logits: lg = sv - sum_m va2[m]*rcp(1+exp2(CE*(x1+y1))) ----
    float q0 = 0.f, q1 = 0.f, q2 = 0.f, q3 = 0.f;
#pragma unroll 4
    for (int m8 = 0; m8 < 16; ++m8) {
      uint4 yv = *((const uint4*)(y1u + ((bb * 16 + m8) * 64 + lane) * 4));
      float4 xa = *((const float4*)(x1c_s + bb * 128 + m8 * 8));
      float4 xb = *((const float4*)(x1c_s + bb * 128 + m8 * 8 + 4));
      float4 va = *((const float4*)(va2_s + m8 * 8));
      float4 vb = *((const float4*)(va2_s + m8 * 8 + 4));
      h2 p;
      p = as_h2(yv.x);
      q0 = fmaf(va.x, rcp1(FEXP(fmaf((float)p.x, CE, xa.x))), q0);
      q1 = fmaf(va.y, rcp1(FEXP(fmaf((float)p.y, CE, xa.y))), q1);
      p = as_h2(yv.y);
      q2 = fmaf(va.z, rcp1(FEXP(fmaf((float)p.x, CE, xa.z))), q2);
      q3 = fmaf(va.w, rcp1(FEXP(fmaf((float)p.y, CE, xa.w))), q3);
      p = as_h2(yv.z);
      q0 = fmaf(vb.x, rcp1(FEXP(fmaf((float)p.x, CE, xb.x))), q0);
      q1 = fmaf(vb.y, rcp1(FEXP(fmaf((float)p.y, CE, xb.y))), q1);
      p = as_h2(yv.w);
      q2 = fmaf(vb.z, rcp1(FEXP(fmaf((float)p.x, CE, xb.z))), q2);
      q3 = fmaf(vb.w, rcp1(FEXP(fmaf((float)p.y, CE, xb.w))), q3);
    }
    float lg = sv - (q0 + q1 + q2 + q3);

    // ---- softmax over l (in-wave), y_til ----
    float mx = lg;
#pragma unroll
    for (int off = 32; off; off >>= 1) mx = fmaxf(mx, __shfl_xor(mx, off, 64));
    float pexp = __expf(lg - mx);
    float smv = pexp, yt = pexp * eproj;
#pragma unroll
    for (int off = 32; off; off >>= 1) {
      smv += __shfl_xor(smv, off, 64);
      yt += __shfl_xor(yt, off, 64);
    }
    float rs = fast_rcp(smv);
    beta_sv = pexp * rs;
    float ytil = yt * rs + y[(size_t)b * Tn + t] * wt_y + wt_b0;

    // ---- gates = ytil*W_ih + b + d @ W_hh^T ----
    float g0 = bias[0] + ytil * wih[0], g1 = bias[1] + ytil * wih[1];
    float g2 = bias[2] + ytil * wih[2], g3 = bias[3] + ytil * wih[3];
    float g4 = bias[4] + ytil * wih[4], g5 = bias[5] + ytil * wih[5];
    float g6 = bias[6] + ytil * wih[6], g7 = bias[7] + ytil * wih[7];
#define GSTEP(PR, K2)                                          \
    {                                                          \
      uint4 wa = whh4[((K2) * 64 + j) * 2];                    \
      uint4 wb = whh4[((K2) * 64 + j) * 2 + 1];                \
      g0 = dot2h(PR, wa.x, g0); g1 = dot2h(PR, wa.y, g1);      \
      g2 = dot2h(PR, wa.z, g2); g3 = dot2h(PR, wa.w, g3);      \
      g4 = dot2h(PR, wb.x, g4); g5 = dot2h(PR, wb.y, g5);      \
      g6 = dot2h(PR, wb.z, g6); g7 = dot2h(PR, wb.w, g7);      \
    }
#pragma unroll 2
    for (int it = 0; it < 16; ++it) {
      uint4 dp = *((const uint4*)(cat_u + bb * 128 + it * 4));
      GSTEP(dp.x, it * 4 + 0)
      GSTEP(dp.y, it * 4 + 1)
      GSTEP(dp.z, it * 4 + 2)
      GSTEP(dp.w, it * 4 + 3)
    }
#undef GSTEP

    // ---- LSTM pointwise ----
    float i0 = fast_sig(g0), i1 = fast_sig(g1);
    float f0 = fast_sig(g2), f1 = fast_sig(g3);
    float gg0 = fast_tanh(g4), gg1 = fast_tanh(g5);
    float o0 = fast_sig(g6), o1 = fast_sig(g7);
    s0 = f0 * s0 + i0 * gg0;
    s1 = f1 * s1 + i1 * gg1;
    float d0 = o0 * fast_tanh(s0);
    float d1 = o1 * fast_tanh(s1);
    cat_u[bb * 128 + j] = pkh(d0, d1);
    cat_u[bb * 128 + 64 + j] = pkh(s0, s1);

    // ---- on-line W_dec accumulation (block t+1) ----
#pragma unroll 4
    for (int it = 0; it < 16; ++it) {
      uint4 dp = *((const uint4*)(cat_u + bb * 128 + it * 4));
      uint2 w0 = wdc2[(t * 64 + it * 4 + 0) * 64 + j];
      uint2 w1 = wdc2[(t * 64 + it * 4 + 1) * 64 + j];
      uint2 w2 = wdc2[(t * 64 + it * 4 + 2) * 64 + j];
      uint2 w3 = wdc2[(t * 64 + it * 4 + 3) * 64 + j];
      df0a = dot2h(dp.x, w0.x, df0a); df1a = dot2h(dp.x, w0.y, df1a);
      df0b = dot2h(dp.y, w1.x, df0b); df1b = dot2h(dp.y, w1.y, df1b);
      df0a = dot2h(dp.z, w2.x, df0a); df1a = dot2h(dp.z, w2.y, df1a);
      df0b = dot2h(dp.w, w3.x, df0b); df1b = dot2h(dp.w, w3.y, df1b);
    }
  }

  // ---------- Phase 2: c_T, final head ----------
  float df0 = df0a + df0b, df1 = df1a + df1b;
  float* beta_s = e_proj_s;  // e_proj cached in regs; safe to reuse
  beta_s[bb * 64 + lane] = beta_sv;
  float c0 = 0.f, c1 = 0.f;
#pragma unroll 2
  for (int it = 0; it < 16; ++it) {
    float4 bv = *((const float4*)(beta_s + bb * 64 + it * 4));
    float2 e0 = *((const float2*)(enc + ((size_t)b * 64 + it * 4 + 0) * 128 + 2 * j));
    float2 e1 = *((const float2*)(enc + ((size_t)b * 64 + it * 4 + 1) * 128 + 2 * j));
    float2 e2 = *((const float2*)(enc + ((size_t)b * 64 + it * 4 + 2) * 128 + 2 * j));
    float2 e3 = *((const float2*)(enc + ((size_t)b * 64 + it * 4 + 3) * 128 + 2 * j));
    c0 = fmaf(bv.x, e0.x, c0); c1 = fmaf(bv.x, e0.y, c1);
    c0 = fmaf(bv.y, e1.x, c0); c1 = fmaf(bv.y, e1.y, c1);
    c0 = fmaf(bv.z, e2.x, c0); c1 = fmaf(bv.z, e2.y, c1);
    c0 = fmaf(bv.w, e3.x, c0); c1 = fmaf(bv.w, e3.y, c1);
  }
  *((float2*)(cat2_s + bb * 256 + 2 * j)) = make_float2(df0, df1);
  *((float2*)(cat2_s + bb * 256 + 128 + 2 * j)) = make_float2(c0, c1);
  float2 hb = *(const float2*)(W_y_b + 2 * j);
  float h0 = hb.x, h1 = hb.y;
#pragma unroll 4
  for (int it = 0; it < 64; ++it) {
    float4 cv = *((const float4*)(cat2_s + bb * 256 + it * 4));
    float2 w0 = *((const float2*)(Wy_pk + ((it * 4 + 0) * 64 + j) * 2));
    float2 w1 = *((const float2*)(Wy_pk + ((it * 4 + 1) * 64 + j) * 2));
    float2 w2 = *((const float2*)(Wy_pk + ((it * 4 + 2) * 64 + j) * 2));
    float2 w3 = *((const float2*)(Wy_pk + ((it * 4 + 3) * 64 + j) * 2));
    h0 = fmaf(cv.x, w0.x, h0); h1 = fmaf(cv.x, w0.y, h1);
    h0 = fmaf(cv.y, w1.x, h0); h1 = fmaf(cv.y, w1.y, h1);
    h0 = fmaf(cv.z, w2.x, h0); h1 = fmaf(cv.z, w2.y, h1);
    h0 = fmaf(cv.w, w3.x, h0); h1 = fmaf(cv.w, w3.y, h1);
  }
  float2 vy = *((const float2*)(v_y_w + 2 * j));
  float r = h0 * vy.x + h1 * vy.y;
#pragma unroll
  for (int off = 32; off; off >>= 1) r += __shfl_xor(r, off, 64);
  if (lane == 0) out[b] = r + v_y_b[0];
}

extern "C" void kernel_launch(void* const* d_in, const int* in_sizes, int n_in,
                              void* d_out, int out_size, void* d_ws, size_t ws_size,
                              hipStream_t stream) {
  const float* enc = (const float*)d_in[0];
  const float* y = (const float*)d_in[1];
  const float* W_d_w = (const float*)d_in[2];
  const float* W_d_b = (const float*)d_in[3];
  const float* U_d_w = (const float*)d_in[4];
  const float* v_d_w = (const float*)d_in[5];
  const float* w_tilda_w = (const float*)d_in[6];
  const float* w_tilda_b = (const float*)d_in[7];
  const float* W_ih = (const float*)d_in[8];
  const float* b_ih = (const float*)d_in[9];
  const float* W_hh = (const float*)d_in[10];
  const float* b_hh = (const float*)d_in[11];
  const float* W_dec_w = (const float*)d_in[12];
  const float* W_dec_b = (const float*)d_in[13];
  const float* W_y_w = (const float*)d_in[14];
  const float* W_y_b = (const float*)d_in[15];
  const float* v_y_w = (const float*)d_in[16];
  const float* v_y_b = (const float*)d_in[17];

  char* ws = (char*)d_ws;
  _Float16* Wd_pk = (_Float16*)(ws + 0);
  _Float16* Whh_pk = (_Float16*)(ws + 65536);
  _Float16* Wdec_pk = (_Float16*)(ws + 196608);
  float* Wy_pk = (float*)(ws + 2293760);
  float* UdT = (float*)(ws + 2424832);

  pack_weights<<<512, 256, 0, stream>>>(W_d_w, W_hh, W_dec_w, W_y_w, U_d_w,
                                        Wd_pk, Whh_pk, Wdec_pk, Wy_pk, UdT);
  fused_main<<<Bn / NB, NTH, LDS_BYTES, stream>>>(
      enc, y, W_d_b, v_d_w, w_tilda_w, w_tilda_b, W_ih, b_ih, b_hh, W_dec_b,
      W_y_b, v_y_w, v_y_b, Wd_pk, Whh_pk, Wdec_pk, Wy_pk, UdT, (float*)d_out);
}

// Round 4
// 2549.756 us; speedup vs baseline: 1.6600x; 1.1639x over previous
//
#include <hip/hip_runtime.h>
#include <hip/hip_bf16.h>

#define Tn 64
#define NB 16
#define NTH 1024

typedef unsigned int u32;
typedef _Float16 h2 __attribute__((ext_vector_type(2)));
typedef __fp16 fp16x2 __attribute__((ext_vector_type(2)));
typedef short s16x8 __attribute__((ext_vector_type(8)));
typedef float f32x4 __attribute__((ext_vector_type(4)));

#define MFMA16(a, b, c) __builtin_amdgcn_mfma_f32_16x16x32_bf16(a, b, c, 0, 0, 0)

__device__ __forceinline__ h2 as_h2(u32 u) { union { u32 u; h2 h; } c; c.u = u; return c.h; }

__device__ __forceinline__ float dot2h(u32 a, u32 w, float acc) {
  return __builtin_amdgcn_fdot2(as_h2(a), as_h2(w), acc, false);
}

__device__ __forceinline__ u32 pkh(float a, float b) {
  union { u32 u; fp16x2 h; } c;
  c.h = __builtin_amdgcn_cvt_pkrtz(a, b);
  return c.u;
}

__device__ __forceinline__ unsigned short bfq(float x) {
  u32 u = __float_as_uint(x);
  return (unsigned short)((u + 0x7fffu + ((u >> 16) & 1)) >> 16);
}

__device__ __forceinline__ u32 pack2bf(float a, float b) {
  u32 ua = __float_as_uint(a), ub = __float_as_uint(b);
  ua = (ua + 0x7fffu + ((ua >> 16) & 1)) >> 16;
  ub = (ub + 0x7fffu + ((ub >> 16) & 1)) >> 16;
  return (ua & 0xffffu) | (ub << 16);
}

#define FEXP(x) __builtin_amdgcn_exp2f(x)
#define CE 2.885390081777927f /* 2*log2(e) */

__device__ __forceinline__ float fast_rcp(float x) { return __builtin_amdgcn_rcpf(x); }
__device__ __forceinline__ float rcp1(float e) { return __builtin_amdgcn_rcpf(1.f + e); }
__device__ __forceinline__ float fast_tanh(float x) {
  float e = __expf(2.f * x);
  return 1.f - 2.f * fast_rcp(1.f + e);
}
__device__ __forceinline__ float fast_sig(float x) {
  return fast_rcp(1.f + __expf(-x));
}

// ---------------- weight pre-pack ----------------
// ws layout (bytes):
//   WdP   bf16 [kk<8][w<8][lane<64][e<8]      @ 0        (65536)
//   WhhP  bf16 [kk<4][nt<32][lane<64][e<8]    @ 65536    (131072)
//   WdecP bf16 [t<65][kk<4][w<8][lane][e<8]   @ 196608   (2129920)
//   UdP   u32-f16pair [k2<64][m<128]          @ 2326528  (32768)
//   wtP   u32-f16pair [k2<64]                 @ 2359296  (256)
//   WyP2  u32-f16pair [k<256][j<64]           @ 2359552  (65536)
__global__ void pack_weights(const float* __restrict__ W_d_w,
                             const float* __restrict__ W_hh,
                             const float* __restrict__ W_dec_w,
                             const float* __restrict__ W_y_w,
                             const float* __restrict__ U_d_w,
                             const float* __restrict__ w_tilda_w,
                             short* __restrict__ WdP, short* __restrict__ WhhP,
                             short* __restrict__ WdecP, u32* __restrict__ UdP,
                             u32* __restrict__ wtP, u32* __restrict__ WyP2) {
  const int i0 = blockIdx.x * blockDim.x + threadIdx.x;
  const int stride = gridDim.x * blockDim.x;
  for (int i = i0; i < 32768; i += stride) {  // WdP
    int e = i & 7, lane = (i >> 3) & 63, w = (i >> 9) & 7, kk = i >> 12;
    int n = w * 16 + (lane & 15), k = kk * 32 + (lane >> 4) * 8 + e;
    WdP[i] = (short)bfq(W_d_w[n * 256 + k]);
  }
  for (int i = i0; i < 65536; i += stride) {  // WhhP
    int e = i & 7, lane = (i >> 3) & 63, nt = (i >> 9) & 31, kk = i >> 14;
    int n = nt * 16 + (lane & 15), k = kk * 32 + (lane >> 4) * 8 + e;
    WhhP[i] = (short)bfq(W_hh[n * 128 + k]);
  }
  for (int i = i0; i < 1064960; i += stride) {  // WdecP (blocks 0..64)
    int e = i & 7, lane = (i >> 3) & 63, w = (i >> 9) & 7, kk = (i >> 12) & 3, tt = i >> 14;
    int n = w * 16 + (lane & 15), k = kk * 32 + (lane >> 4) * 8 + e;
    WdecP[i] = (short)bfq(W_dec_w[n * 8320 + tt * 128 + k]);
  }
  for (int i = i0; i < 8192; i += stride) {  // UdP
    int m = i & 127, k2 = i >> 7;
    UdP[i] = pkh(U_d_w[m * 128 + 2 * k2], U_d_w[m * 128 + 2 * k2 + 1]);
  }
  for (int i = i0; i < 64; i += stride)  // wtP
    wtP[i] = pkh(w_tilda_w[2 * i], w_tilda_w[2 * i + 1]);
  for (int i = i0; i < 16384; i += stride) {  // WyP2
    int jj = i & 63, k = i >> 6;
    WyP2[i] = pkh(W_y_w[(2 * jj) * 256 + k], W_y_w[(2 * jj + 1) * 256 + k]);
  }
}

// ---------------- fused scan ----------------
// LDS (bytes):
//   cat   u32 [16][132]   @ 0      (8448)   d pairs 0..63, s pairs 64..127, pad 128..131
//   x1c   f32 [16][128]   @ 8448   (8192)   CE*(x1+bias)
//   gates f32 [16][512]   @ 16640  (32768)
//   va2   f32 [128]       @ 49408  (512)
//   beta  f32 [16][64]    @ 49920  (4096)
//   cat2  f32 [16][256]   @ 54016  (16384)  [d_fin | c_T]
#define LDS_BYTES 70400

__global__ __launch_bounds__(NTH) void fused_main(
    const float* __restrict__ enc, const float* __restrict__ y,
    const float* __restrict__ W_d_b, const float* __restrict__ v_d_w,
    const float* __restrict__ w_tilda_w, const float* __restrict__ w_tilda_b,
    const float* __restrict__ W_ih, const float* __restrict__ b_ih,
    const float* __restrict__ b_hh, const float* __restrict__ W_dec_b,
    const float* __restrict__ W_y_b, const float* __restrict__ v_y_w,
    const float* __restrict__ v_y_b,
    const short* __restrict__ WdP, const short* __restrict__ WhhP,
    const short* __restrict__ WdecP, const uint4* __restrict__ UdP4,
    const u32* __restrict__ wtP, const u32* __restrict__ WyP2,
    float* __restrict__ out) {
  extern __shared__ char lds[];
  u32* cat_u = (u32*)lds;
  float* x1c = (float*)(lds + 8448);
  float* gates = (float*)(lds + 16640);
  float* va2 = (float*)(lds + 49408);
  float* beta_s = (float*)(lds + 49920);
  float* cat2 = (float*)(lds + 54016);

  const int tid = threadIdx.x;
  const int lane = tid & 63;
  const int wv = tid >> 6;  // 0..15 == bb
  const int b = blockIdx.x * NB + wv;
  const int j = lane;

  for (int i = tid; i < 2112; i += NTH) cat_u[i] = 0u;
  if (wv == 0) {
    va2[lane] = 2.f * v_d_w[lane];
    va2[64 + lane] = 2.f * v_d_w[64 + lane];
  }

  // ---- phase 0: y1 into 64 VGPRs (f16 pairs) + e_proj ----
  const float* enc_row = enc + ((size_t)b * 64 + lane) * 128;
  float ew = 0.f;
  u32 y1p[64];
#pragma unroll
  for (int h = 0; h < 2; ++h) {
    float acc[64];
#pragma unroll
    for (int i = 0; i < 64; ++i) acc[i] = 0.f;
    for (int k2 = 0; k2 < 64; ++k2) {
      float2 ev = *(const float2*)(enc_row + 2 * k2);
      u32 ep = pkh(ev.x, ev.y);
      if (h == 0) ew = dot2h(ep, wtP[k2], ew);
#pragma unroll
      for (int mm = 0; mm < 16; ++mm) {
        uint4 uv = UdP4[k2 * 32 + h * 16 + mm];
        acc[mm * 4 + 0] = dot2h(ep, uv.x, acc[mm * 4 + 0]);
        acc[mm * 4 + 1] = dot2h(ep, uv.y, acc[mm * 4 + 1]);
        acc[mm * 4 + 2] = dot2h(ep, uv.z, acc[mm * 4 + 2]);
        acc[mm * 4 + 3] = dot2h(ep, uv.w, acc[mm * 4 + 3]);
      }
    }
#pragma unroll
    for (int i = 0; i < 32; ++i) y1p[h * 32 + i] = pkh(acc[2 * i], acc[2 * i + 1]);
  }

  // persistent per-lane constants
  float bias[8], wih[8];
#pragma unroll
  for (int c = 0; c < 4; ++c) {
    float2 bi = *(const float2*)(b_ih + c * 128 + 2 * j);
    float2 bh = *(const float2*)(b_hh + c * 128 + 2 * j);
    float2 wi = *(const float2*)(W_ih + c * 128 + 2 * j);
    bias[2 * c] = bi.x + bh.x; bias[2 * c + 1] = bi.y + bh.y;
    wih[2 * c] = wi.x; wih[2 * c + 1] = wi.y;
  }
  const float wt_y = w_tilda_w[128];
  const float wt_b0 = w_tilda_b[0];
  float sv = v_d_w[lane] + v_d_w[64 + lane];
#pragma unroll
  for (int off = 32; off; off >>= 1) sv += __shfl_xor(sv, off, 64);

  const float wdb_n = W_d_b[(wv & 7) * 16 + (lane & 15)];
  const float dfb_n = W_dec_b[(wv & 7) * 16 + (lane & 15)];
  f32x4 dfacc = {dfb_n, dfb_n, dfb_n, dfb_n};
  float s0 = 0.f, s1 = 0.f, beta_sv = 0.f;
  const int arow = (lane & 15) * 132 + (lane >> 4) * 4;  // u32 index of A-frag
  const int crow = (lane >> 4) * 4;                      // C-frag row base
  const int ccol = lane & 15;

  __syncthreads();

#pragma unroll 1
  for (int t = 0; t < Tn; ++t) {
    // ---- phase A: GEMMs on the matrix pipe ----
    if (wv < 8) {
      f32x4 c1 = {wdb_n, wdb_n, wdb_n, wdb_n};
#pragma unroll
      for (int kk = 0; kk < 8; ++kk) {
        s16x8 a = *(const s16x8*)(cat_u + arow + kk * 16);
        s16x8 bf = *(const s16x8*)(WdP + (((kk * 8 + wv) * 64 + lane) * 8));
        c1 = MFMA16(a, bf, c1);
      }
#pragma unroll
      for (int r = 0; r < 4; ++r)
        x1c[(crow + r) * 128 + wv * 16 + ccol] = c1[r] * CE;
    } else {
      const int w8 = wv - 8;
#pragma unroll
      for (int kk = 0; kk < 4; ++kk) {
        s16x8 a = *(const s16x8*)(cat_u + arow + kk * 16);
        s16x8 bf = *(const s16x8*)(WdecP + ((((t * 4 + kk) * 8 + w8) * 64 + lane) * 8));
        dfacc = MFMA16(a, bf, dfacc);
      }
    }
#pragma unroll
    for (int it = 0; it < 2; ++it) {
      f32x4 c2 = {0.f, 0.f, 0.f, 0.f};
      const int nt = wv * 2 + it;
#pragma unroll
      for (int kk = 0; kk < 4; ++kk) {
        s16x8 a = *(const s16x8*)(cat_u + arow + kk * 16);
        s16x8 bf = *(const s16x8*)(WhhP + (((kk * 32 + nt) * 64 + lane) * 8));
        c2 = MFMA16(a, bf, c2);
      }
#pragma unroll
      for (int r = 0; r < 4; ++r)
        gates[(crow + r) * 512 + nt * 16 + ccol] = c2[r];
    }
    __syncthreads();

    // ---- phase B: logits, softmax, LSTM pointwise (wave = batch row) ----
    float q0 = 0.f, q1 = 0.f, q2 = 0.f, q3 = 0.f;
#pragma unroll
    for (int i8 = 0; i8 < 16; ++i8) {
      float4 xa = *(const float4*)(x1c + wv * 128 + i8 * 8);
      float4 xb = *(const float4*)(x1c + wv * 128 + i8 * 8 + 4);
      float4 va = *(const float4*)(va2 + i8 * 8);
      float4 vb = *(const float4*)(va2 + i8 * 8 + 4);
      h2 p;
      p = as_h2(y1p[i8 * 4 + 0]);
      q0 = fmaf(va.x, rcp1(FEXP(fmaf((float)p.x, CE, xa.x))), q0);
      q1 = fmaf(va.y, rcp1(FEXP(fmaf((float)p.y, CE, xa.y))), q1);
      p = as_h2(y1p[i8 * 4 + 1]);
      q2 = fmaf(va.z, rcp1(FEXP(fmaf((float)p.x, CE, xa.z))), q2);
      q3 = fmaf(va.w, rcp1(FEXP(fmaf((float)p.y, CE, xa.w))), q3);
      p = as_h2(y1p[i8 * 4 + 2]);
      q0 = fmaf(vb.x, rcp1(FEXP(fmaf((float)p.x, CE, xb.x))), q0);
      q1 = fmaf(vb.y, rcp1(FEXP(fmaf((float)p.y, CE, xb.y))), q1);
      p = as_h2(y1p[i8 * 4 + 3]);
      q2 = fmaf(vb.z, rcp1(FEXP(fmaf((float)p.x, CE, xb.z))), q2);
      q3 = fmaf(vb.w, rcp1(FEXP(fmaf((float)p.y, CE, xb.w))), q3);
    }
    float lg = sv - (q0 + q1 + q2 + q3);  // |lg| bounded ~15: skip max pass
    float pexp = __expf(lg);
    float smv = pexp, yt = pexp * ew;
#pragma unroll
    for (int off = 32; off; off >>= 1) {
      smv += __shfl_xor(smv, off, 64);
      yt += __shfl_xor(yt, off, 64);
    }
    float rs = fast_rcp(smv);
    beta_sv = pexp * rs;
    float ytil = yt * rs + y[(size_t)b * 64 + t] * wt_y + wt_b0;

    float2 gi = *(const float2*)(gates + wv * 512 + 2 * j);
    float2 gf = *(const float2*)(gates + wv * 512 + 128 + 2 * j);
    float2 gg = *(const float2*)(gates + wv * 512 + 256 + 2 * j);
    float2 go = *(const float2*)(gates + wv * 512 + 384 + 2 * j);
    float i0 = fast_sig(gi.x + bias[0] + ytil * wih[0]);
    float i1 = fast_sig(gi.y + bias[1] + ytil * wih[1]);
    float f0 = fast_sig(gf.x + bias[2] + ytil * wih[2]);
    float f1 = fast_sig(gf.y + bias[3] + ytil * wih[3]);
    float g0 = fast_tanh(gg.x + bias[4] + ytil * wih[4]);
    float g1 = fast_tanh(gg.y + bias[5] + ytil * wih[5]);
    float o0 = fast_sig(go.x + bias[6] + ytil * wih[6]);
    float o1 = fast_sig(go.y + bias[7] + ytil * wih[7]);
    s0 = f0 * s0 + i0 * g0;
    s1 = f1 * s1 + i1 * g1;
    float d0 = o0 * fast_tanh(s0);
    float d1 = o1 * fast_tanh(s1);
    cat_u[wv * 132 + j] = pack2bf(d0, d1);
    cat_u[wv * 132 + 64 + j] = pack2bf(s0, s1);
    __syncthreads();
  }

  // ---- epilogue: d_64 * Wdec block 64, write d_fin ----
  if (wv >= 8) {
    const int w8 = wv - 8;
#pragma unroll
    for (int kk = 0; kk < 4; ++kk) {
      s16x8 a = *(const s16x8*)(cat_u + arow + kk * 16);
      s16x8 bf = *(const s16x8*)(WdecP + ((((64 * 4 + kk) * 8 + w8) * 64 + lane) * 8));
      dfacc = MFMA16(a, bf, dfacc);
    }
#pragma unroll
    for (int r = 0; r < 4; ++r)
      cat2[(crow + r) * 256 + w8 * 16 + ccol] = dfacc[r];
  }
  beta_s[wv * 64 + lane] = beta_sv;
  __syncthreads();

  // ---- c_T and final head (per wave) ----
  float c0 = 0.f, c1v = 0.f;
#pragma unroll 2
  for (int it = 0; it < 16; ++it) {
    float4 bv = *(const float4*)(beta_s + wv * 64 + it * 4);
    float2 e0 = *(const float2*)(enc + ((size_t)b * 64 + it * 4 + 0) * 128 + 2 * j);
    float2 e1 = *(const float2*)(enc + ((size_t)b * 64 + it * 4 + 1) * 128 + 2 * j);
    float2 e2 = *(const float2*)(enc + ((size_t)b * 64 + it * 4 + 2) * 128 + 2 * j);
    float2 e3 = *(const float2*)(enc + ((size_t)b * 64 + it * 4 + 3) * 128 + 2 * j);
    c0 = fmaf(bv.x, e0.x, c0); c1v = fmaf(bv.x, e0.y, c1v);
    c0 = fmaf(bv.y, e1.x, c0); c1v = fmaf(bv.y, e1.y, c1v);
    c0 = fmaf(bv.z, e2.x, c0); c1v = fmaf(bv.z, e2.y, c1v);
    c0 = fmaf(bv.w, e3.x, c0); c1v = fmaf(bv.w, e3.y, c1v);
  }
  *(float2*)(cat2 + wv * 256 + 128 + 2 * j) = make_float2(c0, c1v);

  float2 hb = *(const float2*)(W_y_b + 2 * j);
  float h0 = hb.x, h1 = hb.y;
#pragma unroll 4
  for (int it = 0; it < 64; ++it) {
    float4 cv = *(const float4*)(cat2 + wv * 256 + it * 4);
    u32 w0 = WyP2[(it * 4 + 0) * 64 + j];
    u32 w1 = WyP2[(it * 4 + 1) * 64 + j];
    u32 w2 = WyP2[(it * 4 + 2) * 64 + j];
    u32 w3 = WyP2[(it * 4 + 3) * 64 + j];
    h2 p0 = as_h2(w0), p1 = as_h2(w1), p2 = as_h2(w2), p3 = as_h2(w3);
    h0 = fmaf(cv.x, (float)p0.x, h0); h1 = fmaf(cv.x, (float)p0.y, h1);
    h0 = fmaf(cv.y, (float)p1.x, h0); h1 = fmaf(cv.y, (float)p1.y, h1);
    h0 = fmaf(cv.z, (float)p2.x, h0); h1 = fmaf(cv.z, (float)p2.y, h1);
    h0 = fmaf(cv.w, (float)p3.x, h0); h1 = fmaf(cv.w, (float)p3.y, h1);
  }
  float2 vy = *(const float2*)(v_y_w + 2 * j);
  float r = h0 * vy.x + h1 * vy.y;
#pragma unroll
  for (int off = 32; off; off >>= 1) r += __shfl_xor(r, off, 64);
  if (lane == 0) out[b] = r + v_y_b[0];
}

extern "C" void kernel_launch(void* const* d_in, const int* in_sizes, int n_in,
                              void* d_out, int out_size, void* d_ws, size_t ws_size,
                              hipStream_t stream) {
  const float* enc = (const float*)d_in[0];
  const float* y = (const float*)d_in[1];
  const float* W_d_w = (const float*)d_in[2];
  const float* W_d_b = (const float*)d_in[3];
  const float* U_d_w = (const float*)d_in[4];
  const float* v_d_w = (const float*)d_in[5];
  const float* w_tilda_w = (const float*)d_in[6];
  const float* w_tilda_b = (const float*)d_in[7];
  const float* W_ih = (const float*)d_in[8];
  const float* b_ih = (const float*)d_in[9];
  const float* W_hh = (const float*)d_in[10];
  const float* b_hh = (const float*)d_in[11];
  const float* W_dec_w = (const float*)d_in[12];
  const float* W_dec_b = (const float*)d_in[13];
  const float* W_y_w = (const float*)d_in[14];
  const float* W_y_b = (const float*)d_in[15];
  const float* v_y_w = (const float*)d_in[16];
  const float* v_y_b = (const float*)d_in[17];

  char* ws = (char*)d_ws;
  short* WdP = (short*)(ws + 0);
  short* WhhP = (short*)(ws + 65536);
  short* WdecP = (short*)(ws + 196608);
  u32* UdP = (u32*)(ws + 2326528);
  u32* wtP = (u32*)(ws + 2359296);
  u32* WyP2 = (u32*)(ws + 2359552);

  pack_weights<<<512, 256, 0, stream>>>(W_d_w, W_hh, W_dec_w, W_y_w, U_d_w,
                                        w_tilda_w, WdP, WhhP, WdecP, UdP, wtP, WyP2);
  fused_main<<<4096 / NB, NTH, LDS_BYTES, stream>>>(
      enc, y, W_d_b, v_d_w, w_tilda_w, w_tilda_b, W_ih, b_ih, b_hh, W_dec_b,
      W_y_b, v_y_w, v_y_b, WdP, WhhP, WdecP, (const uint4*)UdP, wtP, WyP2,
      (float*)d_out);
}